// Round 2
// baseline (107.210 us; speedup 1.0000x reference)
//
#include <hip/hip_runtime.h>
#include <stdint.h>

#define NUM_PIDS 20000
#define NCOPIES 8                    // one table copy per XCD (real XCC_ID)
#define TBL_ELEMS (NUM_PIDS * NCOPIES)
#define FIX_SCALE 1048576.0f         // 2^20 fixed point for mse sum
#define CNT_SHIFT 44
#define FIX_MASK ((1ULL << CNT_SHIFT) - 1)

// ws layout: [ u64 tbl[NCOPIES][NUM_PIDS] | float acc[2] ]
// acc[0] = sum of per-pid means, acc[1] = K (present pid count)

__device__ __forceinline__ int xcd_id() {
    int x;
    // HW_REG_XCC_ID verified on gfx950 [learn_hip m09]; wave-uniform SGPR.
    asm volatile("s_getreg_b32 %0, hwreg(HW_REG_XCC_ID)" : "=s"(x));
    return x & (NCOPIES - 1);
}

__global__ void zero_ws_kernel(unsigned long long* __restrict__ tbl,
                               float* __restrict__ acc) {
    int i = blockIdx.x * blockDim.x + threadIdx.x;
    int stride = gridDim.x * blockDim.x;
    for (; i < TBL_ELEMS; i += stride) tbl[i] = 0ULL;
    if (blockIdx.x == 0 && threadIdx.x < 2) acc[threadIdx.x] = 0.0f;
}

__global__ void __launch_bounds__(256) accum_kernel(
        const float4* __restrict__ pred,
        const float4* __restrict__ track,
        const int* __restrict__ pid,
        const int* __restrict__ recon,
        unsigned long long* __restrict__ tbl,
        int n) {
    // Copy private to this physical XCD: all writers of a given address share
    // one L2, so workgroup-scope (no-sc1) atomics RMW locally in TCC — no
    // cross-fabric line ping-pong. Reduce kernel reads after dispatch-end
    // release (L2 writeback), so no cross-XCD coherence is assumed.
    unsigned long long* mytbl = tbl + xcd_id() * NUM_PIDS;
    int i = blockIdx.x * blockDim.x + threadIdx.x;
    int stride = gridDim.x * blockDim.x;
    for (; i < n; i += stride) {
        int p = pid[i];
        int r = recon[i];
        if ((r > 0) && (p > 0)) {   // pid 0 and invalid hits excluded by reference
            float4 a0 = pred[2 * i],  a1 = pred[2 * i + 1];
            float4 b0 = track[2 * i], b1 = track[2 * i + 1];
            float d0 = a0.x - b0.x, d1 = a0.y - b0.y;
            float d2 = a0.z - b0.z, d3 = a0.w - b0.w;
            float d4 = a1.x - b1.x, d5 = a1.y - b1.y;
            float d6 = a1.z - b1.z, d7 = a1.w - b1.w;
            float mse = d0*d0 + d1*d1 + d2*d2 + d3*d3
                      + d4*d4 + d5*d5 + d6*d6 + d7*d7;
            // packed: count in bits [44..63], fixed-point (2^-20) mse sum in [0..43]
            unsigned long long fx = (unsigned long long)(mse * FIX_SCALE + 0.5f);
            unsigned long long packed = (1ULL << CNT_SHIFT) | fx;
            __hip_atomic_fetch_add(&mytbl[p], packed,
                                   __ATOMIC_RELAXED, __HIP_MEMORY_SCOPE_WORKGROUP);
        }
    }
}

__global__ void __launch_bounds__(256) reduce_kernel(
        const unsigned long long* __restrict__ tbl,
        float* __restrict__ acc) {
    int p = blockIdx.x * blockDim.x + threadIdx.x;
    float mean = 0.0f, pres = 0.0f;
    if (p >= 1 && p < NUM_PIDS) {
        unsigned long long s = 0ULL;
        #pragma unroll
        for (int c = 0; c < NCOPIES; ++c) s += tbl[c * NUM_PIDS + p];
        unsigned int cnt = (unsigned int)(s >> CNT_SHIFT);
        if (cnt > 0) {
            mean = (float)((double)(s & FIX_MASK) * (1.0 / 1048576.0)
                           / (double)cnt);
            pres = 1.0f;
        }
    }
    // wave64 reduce
    #pragma unroll
    for (int off = 32; off > 0; off >>= 1) {
        mean += __shfl_down(mean, off);
        pres += __shfl_down(pres, off);
    }
    __shared__ float smean[4], spres[4];
    int wave = threadIdx.x >> 6;
    int lane = threadIdx.x & 63;
    if (lane == 0) { smean[wave] = mean; spres[wave] = pres; }
    __syncthreads();
    if (threadIdx.x == 0) {
        float m = smean[0] + smean[1] + smean[2] + smean[3];
        float k = spres[0] + spres[1] + spres[2] + spres[3];
        atomicAdd(&acc[0], m);
        atomicAdd(&acc[1], k);
    }
}

__global__ void final_kernel(const float* __restrict__ acc,
                             float* __restrict__ out) {
    if (threadIdx.x == 0 && blockIdx.x == 0) {
        float K = acc[1];
        out[0] = (K > 0.0f) ? (100.0f * acc[0] / K) : 0.0f;
    }
}

extern "C" void kernel_launch(void* const* d_in, const int* in_sizes, int n_in,
                              void* d_out, int out_size, void* d_ws, size_t ws_size,
                              hipStream_t stream) {
    // setup_inputs order: W(0) beta(1) H(2) pred(3) Y(4) particle_id(5)
    //                     track_params(6) reconstructable(7)
    const float* pred  = (const float*)d_in[3];
    const int*   pid   = (const int*)d_in[5];
    const float* track = (const float*)d_in[6];
    const int*   recon = (const int*)d_in[7];
    int n = in_sizes[5];   // N hits

    unsigned long long* tbl = (unsigned long long*)d_ws;
    float* acc = (float*)((char*)d_ws + (size_t)TBL_ELEMS * sizeof(unsigned long long));

    zero_ws_kernel<<<256, 256, 0, stream>>>(tbl, acc);
    accum_kernel<<<2048, 256, 0, stream>>>((const float4*)pred, (const float4*)track,
                                           pid, recon, tbl, n);
    reduce_kernel<<<(NUM_PIDS + 255) / 256, 256, 0, stream>>>(tbl, acc);
    final_kernel<<<1, 64, 0, stream>>>(acc, (float*)d_out);
}

// Round 3
// 62.488 us; speedup vs baseline: 1.7157x; 1.7157x over previous
//
#include <hip/hip_runtime.h>
#include <stdint.h>

#define NUM_PIDS 20000
#define MAXBLK   512           // max per-block partial tables (adaptive to ws_size)
#define ATHREADS 512           // accum block size
#define NCH      8             // reduce stage-1 fan-in chunks
#define FIXB     4096.0f       // 2^12 fixed point for per-hit mse
// LDS cell: count in bits[24:31], fixed-point mse sum in bits[0:23]
// stage-1 u64: count in bits[40:63], fixed-point sum in bits[0:39]

// ws layout: [ u32 tbl[nblk][NUM_PIDS] | u64 tmp[NCH][NUM_PIDS] | float acc[2] ]

__global__ void zero_acc_kernel(float* __restrict__ acc) {
    if (threadIdx.x < 2) acc[threadIdx.x] = 0.0f;
}

__global__ void __launch_bounds__(ATHREADS) accum_kernel(
        const float4* __restrict__ pred,
        const float4* __restrict__ track,
        const int* __restrict__ pid,
        const int* __restrict__ recon,
        unsigned int* __restrict__ tbl,
        int n) {
    __shared__ unsigned int bins[NUM_PIDS];          // 80 KB -> 2 blocks/CU
    for (int j = threadIdx.x; j < NUM_PIDS; j += ATHREADS) bins[j] = 0u;
    __syncthreads();

    int i = blockIdx.x * ATHREADS + threadIdx.x;
    int stride = gridDim.x * ATHREADS;
    for (; i < n; i += stride) {
        int p = pid[i];
        int r = recon[i];
        if ((r > 0) && (p > 0)) {   // pid 0 / invalid hits excluded by reference
            float4 a0 = pred[2 * i],  a1 = pred[2 * i + 1];
            float4 b0 = track[2 * i], b1 = track[2 * i + 1];
            float d0 = a0.x - b0.x, d1 = a0.y - b0.y;
            float d2 = a0.z - b0.z, d3 = a0.w - b0.w;
            float d4 = a1.x - b1.x, d5 = a1.y - b1.y;
            float d6 = a1.z - b1.z, d7 = a1.w - b1.w;
            float mse = d0*d0 + d1*d1 + d2*d2 + d3*d3
                      + d4*d4 + d5*d5 + d6*d6 + d7*d7;
            unsigned int fx = (unsigned int)(mse * FIXB + 0.5f);
            atomicAdd(&bins[p], (1u << 24) | fx);    // LDS atomic, no HBM RMW
        }
    }
    __syncthreads();
    // streamed coalesced flush of the whole partial table (zeros included)
    unsigned int* mytbl = tbl + (size_t)blockIdx.x * NUM_PIDS;
    for (int j = threadIdx.x; j < NUM_PIDS; j += ATHREADS) mytbl[j] = bins[j];
}

// stage 1: sum a chunk of block-tables into u64 tmp[chunk][pid]
__global__ void __launch_bounds__(256) reduce1_kernel(
        const unsigned int* __restrict__ tbl,
        unsigned long long* __restrict__ tmp,
        int nblk) {
    int p = blockIdx.x * 256 + threadIdx.x;
    int c = blockIdx.y;
    if (p >= NUM_PIDS) return;
    int cs = (nblk + NCH - 1) / NCH;
    int b0 = c * cs, b1 = min(nblk, b0 + cs);
    unsigned long long sfx = 0ULL, cnt = 0ULL;
    for (int b = b0; b < b1; ++b) {
        unsigned int v = tbl[(size_t)b * NUM_PIDS + p];   // coalesced
        sfx += (unsigned long long)(v & 0xFFFFFFu);
        cnt += (unsigned long long)(v >> 24);
    }
    tmp[(size_t)c * NUM_PIDS + p] = (cnt << 40) | sfx;
}

// stage 2: fold NCH chunks, compute per-pid mean, block-reduce, 2 atomics/block
__global__ void __launch_bounds__(256) reduce2_kernel(
        const unsigned long long* __restrict__ tmp,
        float* __restrict__ acc) {
    int p = blockIdx.x * 256 + threadIdx.x;
    float mean = 0.0f, pres = 0.0f;
    if (p >= 1 && p < NUM_PIDS) {
        unsigned long long s = 0ULL;
        #pragma unroll
        for (int c = 0; c < NCH; ++c) s += tmp[(size_t)c * NUM_PIDS + p];
        unsigned long long cnt = s >> 40;
        if (cnt > 0) {
            double sum = (double)(s & ((1ULL << 40) - 1)) * (1.0 / 4096.0);
            mean = (float)(sum / (double)cnt);
            pres = 1.0f;
        }
    }
    #pragma unroll
    for (int off = 32; off > 0; off >>= 1) {
        mean += __shfl_down(mean, off);
        pres += __shfl_down(pres, off);
    }
    __shared__ float smean[4], spres[4];
    int wave = threadIdx.x >> 6, lane = threadIdx.x & 63;
    if (lane == 0) { smean[wave] = mean; spres[wave] = pres; }
    __syncthreads();
    if (threadIdx.x == 0) {
        atomicAdd(&acc[0], smean[0] + smean[1] + smean[2] + smean[3]);
        atomicAdd(&acc[1], spres[0] + spres[1] + spres[2] + spres[3]);
    }
}

__global__ void final_kernel(const float* __restrict__ acc,
                             float* __restrict__ out) {
    if (threadIdx.x == 0 && blockIdx.x == 0) {
        float K = acc[1];
        out[0] = (K > 0.0f) ? (100.0f * acc[0] / K) : 0.0f;
    }
}

extern "C" void kernel_launch(void* const* d_in, const int* in_sizes, int n_in,
                              void* d_out, int out_size, void* d_ws, size_t ws_size,
                              hipStream_t stream) {
    // setup_inputs order: W(0) beta(1) H(2) pred(3) Y(4) particle_id(5)
    //                     track_params(6) reconstructable(7)
    const float* pred  = (const float*)d_in[3];
    const int*   pid   = (const int*)d_in[5];
    const float* track = (const float*)d_in[6];
    const int*   recon = (const int*)d_in[7];
    int n = in_sizes[5];   // N hits

    // adaptive partial-table count (one per accum block)
    size_t fixed = (size_t)NCH * NUM_PIDS * 8 + 64;
    int nblk = 8;
    if (ws_size > fixed + (size_t)NUM_PIDS * 4) {
        size_t cap = (ws_size - fixed) / ((size_t)NUM_PIDS * 4);
        nblk = (int)(cap < MAXBLK ? cap : MAXBLK);
        if (nblk < 1) nblk = 1;
    }

    unsigned int* tbl = (unsigned int*)d_ws;
    unsigned long long* tmp =
        (unsigned long long*)((char*)d_ws + (size_t)nblk * NUM_PIDS * 4);
    float* acc = (float*)((char*)tmp + (size_t)NCH * NUM_PIDS * 8);

    zero_acc_kernel<<<1, 64, 0, stream>>>(acc);
    accum_kernel<<<nblk, ATHREADS, 0, stream>>>(
        (const float4*)pred, (const float4*)track, pid, recon, tbl, n);
    dim3 g1((NUM_PIDS + 255) / 256, NCH);
    reduce1_kernel<<<g1, 256, 0, stream>>>(tbl, tmp, nblk);
    reduce2_kernel<<<(NUM_PIDS + 255) / 256, 256, 0, stream>>>(tmp, acc);
    final_kernel<<<1, 64, 0, stream>>>(acc, (float*)d_out);
}